// Round 1
// baseline (503.095 us; speedup 1.0000x reference)
//
#include <hip/hip_runtime.h>

// RoPE: out_even = even*cos - odd*sin; out_odd = even*sin + odd*cos
// xq, xk: (B=2, S=4096, D=4096) f32. freqs_cis: (8192, 2048, 2) f32 = rows of
// 4096 floats [cos0,sin0,cos1,sin1,...]. A float4 of x at within-row float4
// index j needs exactly the freqs float4 at index j of row (start+s).
//
// This version fuses the batch dim (B=2): one thread loads fc ONCE and applies
// it to (b=0, b=1) of both xq and xk. freqs HBM traffic halves. The x/out
// streams (touched exactly once) use nontemporal loads/stores so they don't
// evict the freqs rows from L2/L3 between the b=0 and b=1 uses.

typedef float v4f __attribute__((ext_vector_type(4)));

#define S_LEN 4096
#define ROW4  1024   // 4096 floats per row / 4 per float4

__global__ __launch_bounds__(256) void rope_kernel(
    const v4f* __restrict__ xq,
    const v4f* __restrict__ xk,
    const v4f* __restrict__ freqs,
    const int* __restrict__ start_p,
    v4f* __restrict__ outq,
    v4f* __restrict__ outk,
    long long half4)    // float4 count for ONE batch = S*D/4 = 4,194,304
{
    long long i = (long long)blockIdx.x * blockDim.x + threadIdx.x;
    if (i >= half4) return;

    int s    = (int)(i >> 10);            // row within batch (D/4 = 1024 float4/row)
    int col4 = (int)(i & (ROW4 - 1));
    int pos  = *start_p + s;              // pos < 8192 -> (pos<<10)|col4 fits easily

    // Normal (cached) load: reused across b and across the wave.
    v4f fc = freqs[((long long)pos << 10) | col4];

    long long i1 = i + half4;             // same (s, col4) in batch 1

    // Streaming loads: each element read exactly once -> bypass cache alloc.
    v4f q0 = __builtin_nontemporal_load(xq + i);
    v4f k0 = __builtin_nontemporal_load(xk + i);
    v4f q1 = __builtin_nontemporal_load(xq + i1);
    v4f k1 = __builtin_nontemporal_load(xk + i1);

    v4f oq0, ok0, oq1, ok1;
    oq0.x = q0.x * fc.x - q0.y * fc.y;  oq0.y = q0.x * fc.y + q0.y * fc.x;
    oq0.z = q0.z * fc.z - q0.w * fc.w;  oq0.w = q0.z * fc.w + q0.w * fc.z;

    ok0.x = k0.x * fc.x - k0.y * fc.y;  ok0.y = k0.x * fc.y + k0.y * fc.x;
    ok0.z = k0.z * fc.z - k0.w * fc.w;  ok0.w = k0.z * fc.w + k0.w * fc.z;

    oq1.x = q1.x * fc.x - q1.y * fc.y;  oq1.y = q1.x * fc.y + q1.y * fc.x;
    oq1.z = q1.z * fc.z - q1.w * fc.w;  oq1.w = q1.z * fc.w + q1.w * fc.z;

    ok1.x = k1.x * fc.x - k1.y * fc.y;  ok1.y = k1.x * fc.y + k1.y * fc.x;
    ok1.z = k1.z * fc.z - k1.w * fc.w;  ok1.w = k1.z * fc.w + k1.w * fc.z;

    // Streaming stores: outputs never re-read.
    __builtin_nontemporal_store(oq0, outq + i);
    __builtin_nontemporal_store(ok0, outk + i);
    __builtin_nontemporal_store(oq1, outq + i1);
    __builtin_nontemporal_store(ok1, outk + i1);
}

extern "C" void kernel_launch(void* const* d_in, const int* in_sizes, int n_in,
                              void* d_out, int out_size, void* d_ws, size_t ws_size,
                              hipStream_t stream) {
    const v4f* xq    = (const v4f*)d_in[0];
    const v4f* xk    = (const v4f*)d_in[1];
    const v4f* fc    = (const v4f*)d_in[2];
    const int* start = (const int*)d_in[3];

    long long n     = (long long)in_sizes[0];   // 33,554,432 elements per tensor
    long long half4 = n / 4 / 2;                // 4,194,304 float4 per batch (B=2)

    v4f* outq = (v4f*)d_out;
    v4f* outk = (v4f*)((float*)d_out + n);

    int block = 256;
    unsigned grid = (unsigned)((half4 + block - 1) / block);  // 16384 blocks

    rope_kernel<<<grid, block, 0, stream>>>(xq, xk, fc, start, outq, outk, half4);
}